// Round 9
// baseline (234.863 us; speedup 1.0000x reference)
//
#include <hip/hip_runtime.h>
#include <hip/hip_bf16.h>
#include <hip/hip_cooperative_groups.h>

namespace cg = cooperative_groups;

// Problem constants
#define B_   32
#define N_   128
#define KNB  16
#define C_   1024
#define KER  8
#define DOUT 128      // OUT/KERNEL
#define OUTC 1024

typedef __attribute__((ext_vector_type(8))) short bf16x8;
typedef __attribute__((ext_vector_type(4))) float f32x4;

__device__ __forceinline__ ushort f2bf(float f) {
    unsigned u = __builtin_bit_cast(unsigned, f);
    unsigned r = (u + 0x7FFFu + ((u >> 16) & 1u)) >> 16;
    return (ushort)r;
}

// Fragment-packed layouts (ushort units), identical to R8:
//   Fpack[b][rh][mi][kq][s][lane][8]  (unit = b*8+rh*4+mi, 16384 ushort each)
//   value = F[b*128+rh*64+mi*16+(lane&15)][kq*512+s*32+(lane>>4)*8+j]
//   Wpack[m][ch][nj][kq][s][lane][8]  (unit = m*8+ch*4+nj)
//   value = conv_w[m][kq*512+s*32+(lane>>4)*8+j][ch*64+nj*16+(lane&15)]

// ---------------------------------------------------------------------------
// Single cooperative kernel, 256 blocks x 512 threads.
// Phase 1 (block bid):
//   - A-pack unit (b = bid&31, j = bid>>5): rows b*128+j*16..+16  (XCD-matched:
//     producer bid ≡ b mod 32 -> same XCD as all phase-2 consumers of batch b)
//   - blocks [0,64):   W-pack unit bid
//   - blocks [128,256): edge weights for batch (e&31), slice e>>5
// grid.sync()
// Phase 2 (block bid): b = bid&31, m = bid>>5 — R8's zero-barrier split-K
//   fused GEMM+gather, with explicit 2-deep register pipeline.
// ---------------------------------------------------------------------------
__global__ __launch_bounds__(512, 1) void k_all(const float* __restrict__ F,
                                                const float* __restrict__ W,
                                                const float* __restrict__ centre,
                                                const int* __restrict__ nidx,
                                                const float* __restrict__ gw,
                                                const float* __restrict__ mr,
                                                const float* __restrict__ mt,
                                                const float* __restrict__ pr,
                                                const float* __restrict__ pt,
                                                ushort* __restrict__ Fpack,
                                                ushort* __restrict__ Wpack,
                                                float* __restrict__ ew,
                                                float* __restrict__ out) {
    __shared__ __align__(16) char smem[67584];    // Pt (33KB) then Gt (67.6KB)
    int bid = blockIdx.x;
    int tid = threadIdx.x;

    // ================= Phase 1: pack + edge weights =================
    {
        ushort* Pt = (ushort*)smem;               // [16][1032]
        // ---- A-pack (every block): 16 rows x 1024 k
        int b0 = bid & 31, j0 = bid >> 5;
        int R0 = b0 * 128 + j0 * 16;
        ushort* dst = Fpack + (size_t)(b0 * 8 + j0) * 16384;
#pragma unroll
        for (int it = 0; it < 8; ++it) {
            int f = it * 512 + tid;               // 0..4095 float4-chunks
            int row = f >> 8, c4 = (f & 255) * 4;
            float4 v = *(const float4*)(F + (size_t)(R0 + row) * C_ + c4);
            ushort* d = Pt + row * 1032 + c4;
            d[0] = f2bf(v.x); d[1] = f2bf(v.y); d[2] = f2bf(v.z); d[3] = f2bf(v.w);
        }
        __syncthreads();
#pragma unroll
        for (int it = 0; it < 4; ++it) {
            int c = it * 512 + tid;               // 0..2047 bf16x8 chunks
            int ln = c & 63, s = (c >> 6) & 15, kq = c >> 10;
            int lr = ln & 15, kg = ln >> 4;
            bf16x8 v = *(const bf16x8*)(Pt + lr * 1032 + kq * 512 + s * 32 + kg * 8);
            *(bf16x8*)(dst + (size_t)c * 8) = v;
        }

        if (bid < 64) {
            // ---- W-pack unit bid: 1024 c x 16 d slice
            __syncthreads();                      // A-pack reads of Pt done
            int m  = bid >> 3;
            int D0 = ((bid >> 2) & 1) * 64 + (bid & 3) * 16;
#pragma unroll
            for (int it = 0; it < 8; ++it) {
                int f = it * 512 + tid;           // 0..4095
                int c = f >> 2, q4 = f & 3;
                float4 v = *(const float4*)(W + (size_t)m * (C_ * DOUT) + (size_t)c * DOUT + D0 + q4 * 4);
                Pt[(q4 * 4 + 0) * 1032 + c] = f2bf(v.x);
                Pt[(q4 * 4 + 1) * 1032 + c] = f2bf(v.y);
                Pt[(q4 * 4 + 2) * 1032 + c] = f2bf(v.z);
                Pt[(q4 * 4 + 3) * 1032 + c] = f2bf(v.w);
            }
            __syncthreads();
            ushort* wdst = Wpack + (size_t)bid * 16384;
#pragma unroll
            for (int it = 0; it < 4; ++it) {
                int c = it * 512 + tid;
                int ln = c & 63, s = (c >> 6) & 15, kq = c >> 10;
                int lr = ln & 15, kg = ln >> 4;
                bf16x8 v = *(const bf16x8*)(Pt + lr * 1032 + kq * 512 + s * 32 + kg * 8);
                *(bf16x8*)(wdst + (size_t)c * 8) = v;
            }
        } else if (bid >= 128) {
            // ---- edge weights: block e handles batch e&31, slice e>>5
            int e  = bid - 128;
            int t  = (e & 31) * 2048 + (e >> 5) * 512 + tid;   // global (b,n,k)
            int bn = t >> 4;
            int bb = bn >> 7;
            float2 ci = *(const float2*)(centre + (size_t)bn * 2);
            int j = nidx[t];
            float2 cj = *(const float2*)(centre + (size_t)(bb * N_ + j) * 2);
            float cx = ci.x - cj.x, cy = ci.y - cj.y;
            float rho = sqrtf(cx * cx + cy * cy);
            float theta = atan2f(cx, cy);         // atan2(x, y) per reference
            float w[KER];
            float sum = 0.f;
#pragma unroll
            for (int m = 0; m < KER; ++m) {
                float dr = rho - mr[m];
                float wr = expf(-0.5f * dr * dr / (1e-14f + pr[m] * pr[m]));
                float a1 = fabsf(theta - mt[m]);
                float a2 = fabsf(6.2831853071795864f - a1);
                float am = fminf(a1, a2);
                float wt = expf(-0.5f * am * am / (1e-14f + pt[m] * pt[m]));
                float wv = wr * wt;
                if (isnan(wv)) wv = 0.f;
                w[m] = wv;
                sum += wv;
            }
            float scale = gw[t] / sum;
#pragma unroll
            for (int m = 0; m < KER; ++m) ew[(size_t)t * KER + m] = w[m] * scale;
        }
    }

    __threadfence();                              // device-scope release
    cg::this_grid().sync();

    // ================= Phase 2: fused split-K GEMM + gather =================
    float* Gt = (float*)smem;                     // [128][132]

    int wave = tid >> 6;
    int lane = tid & 63;
    int kq = wave >> 2;            // K-half (0,1)
    int rh = (wave >> 1) & 1;      // 64-row half
    int ch = wave & 1;             // 64-col half
    int lr = lane & 15;
    int kg = lane >> 4;
    int b = bid & 31;
    int m = bid >> 5;

    const ushort* Abase[4];
    const ushort* Bbase[4];
#pragma unroll
    for (int i = 0; i < 4; ++i) {
        Abase[i] = Fpack + ((size_t)(b * 8 + rh * 4 + i) * 16384 + kq * 8192 + lane * 8);
        Bbase[i] = Wpack + ((size_t)(m * 8 + ch * 4 + i) * 16384 + kq * 8192 + lane * 8);
    }

    f32x4 acc[4][4];
#pragma unroll
    for (int i = 0; i < 4; ++i)
#pragma unroll
        for (int j = 0; j < 4; ++j) acc[i][j] = (f32x4){0.f, 0.f, 0.f, 0.f};

    // ---- main loop: explicit 2-deep register pipeline, zero barriers
    bf16x8 av[2][4], bv[2][4];
#pragma unroll
    for (int i = 0; i < 4; ++i) {
        av[0][i] = *(const bf16x8*)(Abase[i]);
        bv[0][i] = *(const bf16x8*)(Bbase[i]);
    }
#pragma unroll
    for (int s = 0; s < 16; ++s) {
        int c = s & 1, nx = c ^ 1;
        if (s + 1 < 16) {
#pragma unroll
            for (int i = 0; i < 4; ++i) {
                av[nx][i] = *(const bf16x8*)(Abase[i] + (s + 1) * 512);
                bv[nx][i] = *(const bf16x8*)(Bbase[i] + (s + 1) * 512);
            }
        }
#pragma unroll
        for (int mi = 0; mi < 4; ++mi)
#pragma unroll
            for (int nj = 0; nj < 4; ++nj)
                acc[mi][nj] = __builtin_amdgcn_mfma_f32_16x16x32_bf16(
                    av[c][mi], bv[c][nj], acc[mi][nj], 0, 0, 0);
    }

    // ---- gather metadata prefetch
    int n = tid >> 2, q = tid & 3;
    const int* ip = nidx + (size_t)(b * N_ + n) * KNB;
    int4 jv0 = *(const int4*)(ip);
    int4 jv1 = *(const int4*)(ip + 4);
    int4 jv2 = *(const int4*)(ip + 8);
    int4 jv3 = *(const int4*)(ip + 12);
    const float* ep = ew + (size_t)(b * N_ + n) * (KNB * KER) + m;
    float wv[KNB];
#pragma unroll
    for (int k = 0; k < KNB; ++k) wv[k] = ep[k * KER];

    // ---- split-K reduction into Gt (C/D layout: row=kg*4+r, col=lane&15)
    __syncthreads();                              // Pt reads long done; claim Gt
    if (kq == 0) {
#pragma unroll
        for (int mi = 0; mi < 4; ++mi)
#pragma unroll
            for (int nj = 0; nj < 4; ++nj)
#pragma unroll
                for (int r = 0; r < 4; ++r) {
                    int grow = rh * 64 + mi * 16 + kg * 4 + r;
                    int gcol = ch * 64 + nj * 16 + lr;
                    Gt[grow * 132 + gcol] = acc[mi][nj][r];
                }
    }
    __syncthreads();
    if (kq == 1) {
#pragma unroll
        for (int mi = 0; mi < 4; ++mi)
#pragma unroll
            for (int nj = 0; nj < 4; ++nj)
#pragma unroll
                for (int r = 0; r < 4; ++r) {
                    int grow = rh * 64 + mi * 16 + kg * 4 + r;
                    int gcol = ch * 64 + nj * 16 + lr;
                    Gt[grow * 132 + gcol] += acc[mi][nj][r];
                }
    }
    __syncthreads();

    // ---- gather + ReLU: thread = (row n, quarter q, 32 cols)
    int rot[8];
#pragma unroll
    for (int i = 0; i < 8; ++i) rot[i] = (q * 4 + i * 4) & 31;
    f32x4 o[8];
#pragma unroll
    for (int i = 0; i < 8; ++i) o[i] = (f32x4){0.f, 0.f, 0.f, 0.f};
    int jarr[KNB] = {jv0.x, jv0.y, jv0.z, jv0.w, jv1.x, jv1.y, jv1.z, jv1.w,
                     jv2.x, jv2.y, jv2.z, jv2.w, jv3.x, jv3.y, jv3.z, jv3.w};
#pragma unroll
    for (int k = 0; k < KNB; ++k) {
        const float* gr = Gt + jarr[k] * 132 + q * 32;
        float w = wv[k];
#pragma unroll
        for (int i = 0; i < 8; ++i) {
            f32x4 v = *(const f32x4*)(gr + rot[i]);
            o[i] += v * w;
        }
    }
    float* op = out + (size_t)(b * N_ + n) * OUTC + m * DOUT + q * 32;
#pragma unroll
    for (int i = 0; i < 8; ++i) {
        f32x4 r = o[i];
#pragma unroll
        for (int jj = 0; jj < 4; ++jj) r[jj] = fmaxf(r[jj], 0.f);
        *(f32x4*)(op + rot[i]) = r;
    }
}

// ---------------------------------------------------------------------------
extern "C" void kernel_launch(void* const* d_in, const int* in_sizes, int n_in,
                              void* d_out, int out_size, void* d_ws, size_t ws_size,
                              hipStream_t stream) {
    const float* node_feats      = (const float*)d_in[0];
    const float* node_centre     = (const float*)d_in[1];
    const int*   neighbor_idx    = (const int*)d_in[2];
    const float* graph_weights   = (const float*)d_in[3];
    const float* mean_rho        = (const float*)d_in[4];
    const float* mean_theta      = (const float*)d_in[5];
    const float* precision_rho   = (const float*)d_in[6];
    const float* precision_theta = (const float*)d_in[7];
    const float* conv_w          = (const float*)d_in[8];
    float* out = (float*)d_out;

    char* ws = (char*)d_ws;
    ushort* Fpack = (ushort*)(ws);                   // 8 MB
    ushort* Wpack = (ushort*)(ws + (8u  << 20));     // 2 MB
    float*  ew    = (float*) (ws + (10u << 20));     // 2 MB

    void* args[] = {(void*)&node_feats, (void*)&conv_w, (void*)&node_centre,
                    (void*)&neighbor_idx, (void*)&graph_weights,
                    (void*)&mean_rho, (void*)&mean_theta,
                    (void*)&precision_rho, (void*)&precision_theta,
                    (void*)&Fpack, (void*)&Wpack, (void*)&ew, (void*)&out};
    hipLaunchCooperativeKernel((const void*)k_all, dim3(256), dim3(512),
                               args, 0, stream);
}

// Round 10
// 112.631 us; speedup vs baseline: 2.0852x; 2.0852x over previous
//
#include <hip/hip_runtime.h>
#include <hip/hip_bf16.h>

// Problem constants
#define B_   32
#define N_   128
#define KNB  16
#define C_   1024
#define KER  8
#define DOUT 128      // OUT/KERNEL
#define OUTC 1024

typedef __attribute__((ext_vector_type(8))) short bf16x8;
typedef __attribute__((ext_vector_type(4))) float f32x4;

__device__ __forceinline__ ushort f2bf(float f) {
    unsigned u = __builtin_bit_cast(unsigned, f);
    unsigned r = (u + 0x7FFFu + ((u >> 16) & 1u)) >> 16;
    return (ushort)r;
}

// Fragment-packed layouts (ushort units), identical to R8:
//   Fpack[b][rh][mi][kq][s][lane][8]  (unit = b*8+rh*4+mi, 16384 ushort each)
//   value = F[b*128+rh*64+mi*16+(lane&15)][kq*512+s*32+(lane>>4)*8+j]
//   Wpack[m][ch][nj][kq][s][lane][8]  (unit = m*8+ch*4+nj)
//   value = conv_w[m][kq*512+s*32+(lane>>4)*8+j][ch*64+nj*16+(lane&15)]
// K-quarter view: offset unit*16384 + kq4*4096 + s*512 + lane*8, s in [0,8).

// ---------------------------------------------------------------------------
// Prep kernel (identical to R8): blocks [0,256):   A-pack  (b,rh,mi) -> Fpack
//                                blocks [256,320): W-pack  (m,ch,nj) -> Wpack
//                                blocks [320,576): edge weights ew
// ---------------------------------------------------------------------------
__global__ __launch_bounds__(256) void k_prep(const float* __restrict__ F,
                                              ushort* __restrict__ Fpack,
                                              const float* __restrict__ W,
                                              ushort* __restrict__ Wpack,
                                              const float* __restrict__ centre,
                                              const int* __restrict__ nidx,
                                              const float* __restrict__ gw,
                                              const float* __restrict__ mr,
                                              const float* __restrict__ mt,
                                              const float* __restrict__ pr,
                                              const float* __restrict__ pt,
                                              float* __restrict__ ew) {
    __shared__ ushort Pt[16 * 1032];          // 33 KB padded tile [16][1032]
    int bid = blockIdx.x;
    int t   = threadIdx.x;

    if (bid < 256) {
        // ---- A-pack: block = (b, rh, mi); 16 rows x 1024 k
        int R0 = bid * 16;
#pragma unroll
        for (int it = 0; it < 16; ++it) {
            float4 v = *(const float4*)(F + (size_t)(R0 + it) * C_ + t * 4);
            ushort* d = Pt + it * 1032 + t * 4;
            d[0] = f2bf(v.x); d[1] = f2bf(v.y); d[2] = f2bf(v.z); d[3] = f2bf(v.w);
        }
        __syncthreads();
        ushort* dst = Fpack + (size_t)bid * 16384;
#pragma unroll
        for (int it = 0; it < 8; ++it) {
            int c  = it * 256 + t;
            int ln = c & 63, s = (c >> 6) & 15, kq = c >> 10;
            int lr = ln & 15, kg = ln >> 4;
            bf16x8 v = *(const bf16x8*)(Pt + lr * 1032 + kq * 512 + s * 32 + kg * 8);
            *(bf16x8*)(dst + (size_t)c * 8) = v;
        }
    } else if (bid < 320) {
        // ---- W-pack: block = (m, ch, nj); 1024 c x 16 d slice
        int b2 = bid - 256;
        int m  = b2 >> 3;
        int D0 = ((b2 >> 2) & 1) * 64 + (b2 & 3) * 16;
#pragma unroll
        for (int it = 0; it < 16; ++it) {
            int f  = it * 256 + t;
            int c  = f >> 2, q4 = f & 3;
            float4 v = *(const float4*)(W + (size_t)m * (C_ * DOUT) + (size_t)c * DOUT + D0 + q4 * 4);
            Pt[(q4 * 4 + 0) * 1032 + c] = f2bf(v.x);
            Pt[(q4 * 4 + 1) * 1032 + c] = f2bf(v.y);
            Pt[(q4 * 4 + 2) * 1032 + c] = f2bf(v.z);
            Pt[(q4 * 4 + 3) * 1032 + c] = f2bf(v.w);
        }
        __syncthreads();
        ushort* dst = Wpack + (size_t)b2 * 16384;
#pragma unroll
        for (int it = 0; it < 8; ++it) {
            int c  = it * 256 + t;
            int ln = c & 63, s = (c >> 6) & 15, kq = c >> 10;
            int lr = ln & 15, kg = ln >> 4;
            bf16x8 v = *(const bf16x8*)(Pt + lr * 1032 + kq * 512 + s * 32 + kg * 8);
            *(bf16x8*)(dst + (size_t)c * 8) = v;
        }
    } else {
        // ---- edge weights: 65536 threads = B*N*K
        int tt = (bid - 320) * 256 + t;
        int bn = tt >> 4;
        int b  = bn >> 7;
        float2 ci = *(const float2*)(centre + (size_t)bn * 2);
        int j = nidx[tt];
        float2 cj = *(const float2*)(centre + (size_t)(b * N_ + j) * 2);
        float cx = ci.x - cj.x, cy = ci.y - cj.y;
        float rho = sqrtf(cx * cx + cy * cy);
        float theta = atan2f(cx, cy);            // atan2(x, y) per reference
        float w[KER];
        float sum = 0.f;
#pragma unroll
        for (int m = 0; m < KER; ++m) {
            float dr = rho - mr[m];
            float wr = expf(-0.5f * dr * dr / (1e-14f + pr[m] * pr[m]));
            float a1 = fabsf(theta - mt[m]);
            float a2 = fabsf(6.2831853071795864f - a1);
            float am = fminf(a1, a2);
            float wt = expf(-0.5f * am * am / (1e-14f + pt[m] * pt[m]));
            float wv = wr * wt;
            if (isnan(wv)) wv = 0.f;
            w[m] = wv;
            sum += wv;
        }
        float scale = gw[tt] / sum;
#pragma unroll
        for (int m = 0; m < KER; ++m) ew[(size_t)tt * KER + m] = w[m] * scale;
    }
}

// ---------------------------------------------------------------------------
// Fused kernel, block bid: b = bid&31, m = bid>>5 (XCD = b%8 shared).
// 1024 threads = 16 waves: wave = (kq4, rh, ch), each computes a 64x64 tile
// over K-quarter kq4*256. Zero-barrier main loop (2-deep register pipeline,
// contiguous packed fragment loads). 4-stage LDS split-K reduction, then
// fused gather+ReLU.
// ---------------------------------------------------------------------------
__global__ __launch_bounds__(1024, 4) void k_fused(const ushort* __restrict__ Fpack,
                                                   const ushort* __restrict__ Wpack,
                                                   const float* __restrict__ ew,
                                                   const int* __restrict__ nidx,
                                                   float* __restrict__ out) {
    __shared__ float Gt[128 * 132];               // 67584 B

    int tid  = threadIdx.x;
    int wave = tid >> 6;
    int lane = tid & 63;
    int kq4 = wave >> 2;           // K-quarter (0..3)
    int rh  = (wave >> 1) & 1;     // 64-row half
    int ch  = wave & 1;            // 64-col half
    int lr = lane & 15;
    int kg = lane >> 4;
    int bid = blockIdx.x;
    int b = bid & 31;
    int m = bid >> 5;

    // per-fragment bases (ushort offsets); s-step adds s*512, s in [0,8)
    const ushort* Abase[4];
    const ushort* Bbase[4];
#pragma unroll
    for (int i = 0; i < 4; ++i) {
        Abase[i] = Fpack + ((size_t)(b * 8 + rh * 4 + i) * 16384 + kq4 * 4096 + lane * 8);
        Bbase[i] = Wpack + ((size_t)(m * 8 + ch * 4 + i) * 16384 + kq4 * 4096 + lane * 8);
    }

    f32x4 acc[4][4];
#pragma unroll
    for (int i = 0; i < 4; ++i)
#pragma unroll
        for (int j = 0; j < 4; ++j) acc[i][j] = (f32x4){0.f, 0.f, 0.f, 0.f};

    // ---- main loop: 8 steps, 2-deep register pipeline, zero barriers
    bf16x8 av[2][4], bv[2][4];
#pragma unroll
    for (int i = 0; i < 4; ++i) {
        av[0][i] = *(const bf16x8*)(Abase[i]);
        bv[0][i] = *(const bf16x8*)(Bbase[i]);
    }
#pragma unroll
    for (int s = 0; s < 8; ++s) {
        int c = s & 1, nx = c ^ 1;
        if (s + 1 < 8) {
#pragma unroll
            for (int i = 0; i < 4; ++i) {
                av[nx][i] = *(const bf16x8*)(Abase[i] + (s + 1) * 512);
                bv[nx][i] = *(const bf16x8*)(Bbase[i] + (s + 1) * 512);
            }
        }
#pragma unroll
        for (int mi = 0; mi < 4; ++mi)
#pragma unroll
            for (int nj = 0; nj < 4; ++nj)
                acc[mi][nj] = __builtin_amdgcn_mfma_f32_16x16x32_bf16(
                    av[c][mi], bv[c][nj], acc[mi][nj], 0, 0, 0);
    }

    // ---- gather metadata loads (after main loop; hidden by reduction stages)
    int n = tid >> 3, q = tid & 7;               // row n, 16-col quarter q
    const int* ip = nidx + (size_t)(b * N_ + n) * KNB;
    int4 jv0 = *(const int4*)(ip);
    int4 jv1 = *(const int4*)(ip + 4);
    int4 jv2 = *(const int4*)(ip + 8);
    int4 jv3 = *(const int4*)(ip + 12);
    const float* ep = ew + (size_t)(b * N_ + n) * (KNB * KER) + m;
    float wv[KNB];
#pragma unroll
    for (int k = 0; k < KNB; ++k) wv[k] = ep[k * KER];

    // ---- 4-stage split-K reduction into Gt (C/D: row=kg*4+r, col=lane&15)
#pragma unroll
    for (int st = 0; st < 4; ++st) {
        if (kq4 == st) {
#pragma unroll
            for (int mi = 0; mi < 4; ++mi)
#pragma unroll
                for (int nj = 0; nj < 4; ++nj)
#pragma unroll
                    for (int r = 0; r < 4; ++r) {
                        int grow = rh * 64 + mi * 16 + kg * 4 + r;
                        int gcol = ch * 64 + nj * 16 + lr;
                        if (st == 0) Gt[grow * 132 + gcol] = acc[mi][nj][r];
                        else         Gt[grow * 132 + gcol] += acc[mi][nj][r];
                    }
        }
        __syncthreads();
    }

    // ---- gather + ReLU: thread = (row n = tid>>3, quarter q = tid&7, 16 cols)
    int rot[4];
#pragma unroll
    for (int i = 0; i < 4; ++i) rot[i] = (q * 4 + i * 4) & 15;
    f32x4 o[4];
#pragma unroll
    for (int i = 0; i < 4; ++i) o[i] = (f32x4){0.f, 0.f, 0.f, 0.f};
    int jarr[KNB] = {jv0.x, jv0.y, jv0.z, jv0.w, jv1.x, jv1.y, jv1.z, jv1.w,
                     jv2.x, jv2.y, jv2.z, jv2.w, jv3.x, jv3.y, jv3.z, jv3.w};
#pragma unroll
    for (int k = 0; k < KNB; ++k) {
        const float* gr = Gt + jarr[k] * 132 + q * 16;
        float w = wv[k];
#pragma unroll
        for (int i = 0; i < 4; ++i) {
            f32x4 v = *(const f32x4*)(gr + rot[i]);
            o[i] += v * w;
        }
    }
    float* op = out + (size_t)(b * N_ + n) * OUTC + m * DOUT + q * 16;
#pragma unroll
    for (int i = 0; i < 4; ++i) {
        f32x4 r = o[i];
#pragma unroll
        for (int jj = 0; jj < 4; ++jj) r[jj] = fmaxf(r[jj], 0.f);
        *(f32x4*)(op + rot[i]) = r;
    }
}

// ---------------------------------------------------------------------------
extern "C" void kernel_launch(void* const* d_in, const int* in_sizes, int n_in,
                              void* d_out, int out_size, void* d_ws, size_t ws_size,
                              hipStream_t stream) {
    const float* node_feats      = (const float*)d_in[0];
    const float* node_centre     = (const float*)d_in[1];
    const int*   neighbor_idx    = (const int*)d_in[2];
    const float* graph_weights   = (const float*)d_in[3];
    const float* mean_rho        = (const float*)d_in[4];
    const float* mean_theta      = (const float*)d_in[5];
    const float* precision_rho   = (const float*)d_in[6];
    const float* precision_theta = (const float*)d_in[7];
    const float* conv_w          = (const float*)d_in[8];
    float* out = (float*)d_out;

    char* ws = (char*)d_ws;
    ushort* Fpack = (ushort*)(ws);                   // 8 MB
    ushort* Wpack = (ushort*)(ws + (8u  << 20));     // 2 MB
    float*  ew    = (float*) (ws + (10u << 20));     // 2 MB

    k_prep<<<576, 256, 0, stream>>>(node_feats, Fpack, conv_w, Wpack,
                                    node_centre, neighbor_idx, graph_weights,
                                    mean_rho, mean_theta,
                                    precision_rho, precision_theta, ew);
    // 256 blocks; bid = m*32 + b so all 8 m-blocks of a batch land on one XCD
    k_fused<<<256, 1024, 0, stream>>>(Fpack, Wpack, ew, neighbor_idx, out);
}